// Round 12
// baseline (573.501 us; speedup 1.0000x reference)
//
#include <hip/hip_runtime.h>

#define N_NODES 40000
#define M_PAD   40064          // 313 * 128
#define M_EDGES 10000
#define NNZ_CNT 400000
#define FT_DIM  128
#define HID     256
#define NCLS    10
#define NG      128
#define EPSV    1e-5f
#define ROWSINV (1.0f / 40000.0f)

#define NBE 79    // edge buckets: key >> 7 (128 keys each)
#define NBN 157   // node buckets: key >> 8 (256 keys each)

typedef short s8v __attribute__((ext_vector_type(8)));
typedef unsigned short u8v __attribute__((ext_vector_type(8)));
typedef float f4v __attribute__((ext_vector_type(4)));
typedef unsigned short u4v __attribute__((ext_vector_type(4)));
typedef unsigned short u2v __attribute__((ext_vector_type(2)));

__device__ __forceinline__ unsigned short f2bf(float x) {
    unsigned int u = __float_as_uint(x);
    u += 0x7fffu + ((u >> 16) & 1u);
    return (unsigned short)(u >> 16);
}
__device__ __forceinline__ float bf2f(unsigned short h) {
    return __uint_as_float(((unsigned int)h) << 16);
}

// blocked-chunk element address (in shorts) for (r, k): layout [r/64][k/8][r%64] 16B chunks
__device__ __forceinline__ long ablk(int r, int k, int K) {
    return ((long)((r >> 6) * (K >> 3) + (k >> 3)) * 64 + (r & 63)) * 8 + (k & 7);
}

// ---------------- utility ----------------
__global__ void fzero(float* __restrict__ p, int n) {
    int i = blockIdx.x * 256 + threadIdx.x;
    if (i < n) p[i] = 0.f;
}

// ---------------- CSR build ----------------
__global__ void count_kernel(const int* __restrict__ ni, const int* __restrict__ ei,
                             int* __restrict__ cnt_e, int* __restrict__ cnt_n) {
    int i = blockIdx.x * 256 + threadIdx.x;
    if (i < NNZ_CNT) {
        atomicAdd(&cnt_e[ei[i]], 1);
        atomicAdd(&cnt_n[ni[i]], 1);
    }
}

__device__ void exscan_body(const int* __restrict__ in, int* __restrict__ out, int n) {
    __shared__ int wsum[16];
    __shared__ int carry_s;
    int tid = threadIdx.x, lane = tid & 63, w = tid >> 6;
    if (tid == 0) carry_s = 0;
    __syncthreads();
    for (int base = 0; base < n; base += 4096) {
        int i0 = base + tid * 4;
        int v[4];
#pragma unroll
        for (int t = 0; t < 4; ++t) v[t] = (i0 + t < n) ? in[i0 + t] : 0;
        int s = v[0] + v[1] + v[2] + v[3];
        int sc = s;
#pragma unroll
        for (int d = 1; d < 64; d <<= 1) {
            int t = __shfl_up(sc, d, 64);
            if (lane >= d) sc += t;
        }
        if (lane == 63) wsum[w] = sc;
        __syncthreads();
        if (tid < 64) {
            int ws = (lane < 16) ? wsum[lane] : 0;
            int wsc = ws;
#pragma unroll
            for (int d = 1; d < 16; d <<= 1) {
                int t = __shfl_up(wsc, d, 64);
                if (lane >= d) wsc += t;
            }
            if (lane < 16) wsum[lane] = wsc - ws;
        }
        __syncthreads();
        int carry = carry_s;
        int ex = carry + wsum[w] + (sc - s);
#pragma unroll
        for (int t = 0; t < 4; ++t) {
            if (i0 + t < n) out[i0 + t] = ex;
            ex += v[t];
        }
        __syncthreads();
        if (tid == 1023) carry_s = ex;
    }
    __syncthreads();
    if (tid == 0) out[n] = carry_s;
}

__global__ __launch_bounds__(1024) void exscan2(const int* __restrict__ ce, int* __restrict__ oe,
                                                const int* __restrict__ cn, int* __restrict__ on_,
                                                int* __restrict__ gcur_e, int* __restrict__ gcur_n) {
    int tid = threadIdx.x;
    if (blockIdx.x == 0) {
        exscan_body(ce, oe, M_EDGES);
        __syncthreads();
        for (int b = tid; b < NBE; b += 1024) gcur_e[b] = oe[b << 7];
    } else {
        exscan_body(cn, on_, N_NODES);
        __syncthreads();
        for (int b = tid; b < NBN; b += 1024) gcur_n[b] = on_[b << 8];
    }
}

// ---- partition: LDS multisplit by bucket, run-burst append into staging ----
template<int NB, int SH, bool EDGE>
__device__ void part_side(const int* __restrict__ key, const int* __restrict__ val,
                          int* __restrict__ gcur, unsigned* __restrict__ stg,
                          unsigned* buf, int* hist, int* loff, int* lcur, int* gbase,
                          int i0, int items) {
    int tid = threadIdx.x;
    for (int b = tid; b < NB; b += 256) hist[b] = 0;
    __syncthreads();
    for (int p = tid; p < items; p += 256) atomicAdd(&hist[key[i0 + p] >> SH], 1);
    __syncthreads();
    if (tid == 0) {
        int s = 0;
        for (int b = 0; b < NB; ++b) { loff[b] = s; s += hist[b]; }
    }
    __syncthreads();
    for (int b = tid; b < NB; b += 256) lcur[b] = loff[b];
    __syncthreads();
    for (int p = tid; p < items; p += 256) {
        int k = key[i0 + p], v = val[i0 + p];
        int pos = atomicAdd(&lcur[k >> SH], 1);
        buf[pos] = EDGE ? (((unsigned)k << 16) | (unsigned)v)
                        : (((unsigned)k << 14) | (unsigned)v);
    }
    __syncthreads();
    for (int b = tid; b < NB; b += 256) gbase[b] = atomicAdd(&gcur[b], hist[b]);
    __syncthreads();
    for (int p = tid; p < items; p += 256) {
        unsigned en = buf[p];
        int k = EDGE ? (int)(en >> 16) : (int)(en >> 14);
        int b = k >> SH;
        stg[gbase[b] + (p - loff[b])] = en;
    }
    __syncthreads();
}

__global__ __launch_bounds__(256) void partition_kernel(const int* __restrict__ ni,
        const int* __restrict__ ei, int* __restrict__ gcur_e, int* __restrict__ gcur_n,
        unsigned* __restrict__ stg_e, unsigned* __restrict__ stg_n) {
    __shared__ unsigned buf[8192];
    __shared__ int hist[160], loff[160], lcur[160], gbase[160];
    int i0 = blockIdx.x * 8192;
    int items = NNZ_CNT - i0;
    if (items > 8192) items = 8192;
    part_side<NBE, 7, true>(ei, ni, gcur_e, stg_e, buf, hist, loff, lcur, gbase, i0, items);
    part_side<NBN, 8, false>(ni, ei, gcur_n, stg_n, buf, hist, loff, lcur, gbase, i0, items);
}

__global__ __launch_bounds__(256) void bucket_fill(const int* __restrict__ off_e,
        const int* __restrict__ off_n, const unsigned* __restrict__ stg_e,
        const unsigned* __restrict__ stg_n, int* __restrict__ idx_e,
        int* __restrict__ idx_n) {
    __shared__ int cur[257];
    int tid = threadIdx.x;
    int b = blockIdx.x;
    if (b < NBE) {
        int k0 = b << 7, k1 = min(k0 + 128, M_EDGES), nk = k1 - k0;
        int base = off_e[k0];
        for (int i = tid; i <= nk; i += 256) cur[i] = off_e[k0 + i] - base;
        __syncthreads();
        int cnt = cur[nk];
        for (int p = tid; p < cnt; p += 256) {
            unsigned en = stg_e[base + p];
            int loc = atomicAdd(&cur[(int)(en >> 16) - k0], 1);
            idx_e[base + loc] = (int)(en & 0xFFFFu);
        }
    } else {
        b -= NBE;
        int k0 = b << 8, k1 = min(k0 + 256, N_NODES), nk = k1 - k0;
        int base = off_n[k0];
        for (int i = tid; i <= nk; i += 256) cur[i] = off_n[k0 + i] - base;
        __syncthreads();
        int cnt = cur[nk];
        for (int p = tid; p < cnt; p += 256) {
            unsigned en = stg_n[base + p];
            int loc = atomicAdd(&cur[(int)(en >> 14) - k0], 1);
            idx_n[base + loc] = (int)(en & 0x3FFFu);
        }
    }
}

__global__ void dinv_kernel(const int* __restrict__ off_n, const int* __restrict__ idx_n,
                            const int* __restrict__ cnt_e, float* __restrict__ dinv) {
    int n = blockIdx.x * 256 + threadIdx.x;
    if (n < N_NODES) {
        int s = off_n[n], e = off_n[n + 1];
        float p = 0.f;
        for (int j = s; j < e; ++j) p += (float)cnt_e[idx_n[j]];
        dinv[n] = (p > 0.f) ? 1.0f / p : 1.0f;
    }
}

// -------- weight prep (all 4 mats): W[K x 256] fp32 -> blocked hi/lo planes --------
struct WPA {
    const float* W[4];
    unsigned short* h[4];
    unsigned short* l[4];
};
__global__ void wprep_all(WPA p) {
    int m = blockIdx.y;
    int K = (m == 0) ? FT_DIM : HID;
    int i = blockIdx.x * 256 + threadIdx.x;
    if (i >= K * 256) return;
    int k = i >> 8, c = i & 255;
    float x = p.W[m][i];
    unsigned short hh = f2bf(x);
    long o = ((long)((c >> 6) * (K >> 3) + (k >> 3)) * 64 + (c & 63)) * 8 + (k & 7);
    p.h[m][o] = hh;
    p.l[m][o] = f2bf(x - bf2f(hh));
}

// ---------------- fp32 -> bf16 (round only, row-major) ----------------
__global__ void fsplit(const float4* __restrict__ src, u4v* __restrict__ h, int n4) {
    int i = blockIdx.x * 256 + threadIdx.x;
    if (i < n4) {
        float4 v = src[i];
        h[i] = (u4v){f2bf(v.x), f2bf(v.y), f2bf(v.z), f2bf(v.w)};
    }
}

// -------- relu(bn(x)) on bf16 src -> blocked single bf16 plane, BN finalize fused --------
__global__ __launch_bounds__(256) void bn_split_blk(const unsigned short* __restrict__ src,
        const float* __restrict__ stats, const float* __restrict__ g,
        const float* __restrict__ be, unsigned short* __restrict__ hOut) {
    __shared__ float sa[HID], sc_[HID];
    int tid = threadIdx.x;
    {
        float mean = stats[tid] * ROWSINV;
        float var = stats[HID + tid] * ROWSINV - mean * mean;
        float av = g[tid] * rsqrtf(var + EPSV);
        sa[tid] = av;
        sc_[tid] = be[tid] - mean * av;
    }
    __syncthreads();
    int r = tid >> 2, kqg = tid & 3;
    long row = (long)blockIdx.x * 64 + r;
    long cbase = ((long)blockIdx.x * 32) * 64 + r;
#pragma unroll
    for (int t = 0; t < 8; ++t) {
        int kq = kqg * 8 + t;
        u8v v = *(const u8v*)(src + row * HID + kq * 8);
        float4 a0 = *(const float4*)(sa + kq * 8);
        float4 a1 = *(const float4*)(sa + kq * 8 + 4);
        float4 c0 = *(const float4*)(sc_ + kq * 8);
        float4 c1 = *(const float4*)(sc_ + kq * 8 + 4);
        s8v h;
        h[0] = (short)f2bf(fmaxf(fmaf(a0.x, bf2f(v[0]), c0.x), 0.f));
        h[1] = (short)f2bf(fmaxf(fmaf(a0.y, bf2f(v[1]), c0.y), 0.f));
        h[2] = (short)f2bf(fmaxf(fmaf(a0.z, bf2f(v[2]), c0.z), 0.f));
        h[3] = (short)f2bf(fmaxf(fmaf(a0.w, bf2f(v[3]), c0.w), 0.f));
        h[4] = (short)f2bf(fmaxf(fmaf(a1.x, bf2f(v[4]), c1.x), 0.f));
        h[5] = (short)f2bf(fmaxf(fmaf(a1.y, bf2f(v[5]), c1.y), 0.f));
        h[6] = (short)f2bf(fmaxf(fmaf(a1.z, bf2f(v[6]), c1.z), 0.f));
        h[7] = (short)f2bf(fmaxf(fmaf(a1.w, bf2f(v[7]), c1.w), 0.f));
        *(s8v*)(hOut + (cbase + (long)kq * 64) * 8) = h;
    }
}

// -------- relu(bn(x)) on bf16 src -> row-major bf16, BN finalize fused --------
__global__ __launch_bounds__(256) void bn_rowmajor(const u8v* __restrict__ src,
        const float* __restrict__ stats, const float* __restrict__ g,
        const float* __restrict__ be, u8v* __restrict__ hOut, int n8) {
    __shared__ float sa[HID], sc_[HID];
    int tid = threadIdx.x;
    {
        float mean = stats[tid] * ROWSINV;
        float var = stats[HID + tid] * ROWSINV - mean * mean;
        float av = g[tid] * rsqrtf(var + EPSV);
        sa[tid] = av;
        sc_[tid] = be[tid] - mean * av;
    }
    __syncthreads();
    int i = blockIdx.x * 256 + tid;
    if (i >= n8) return;
    int col = (i << 3) & (HID - 1);
    u8v v = src[i];
    u8v o;
#pragma unroll
    for (int q = 0; q < 8; ++q)
        o[q] = f2bf(fmaxf(fmaf(sa[col + q], bf2f(v[q]), sc_[col + q]), 0.f));
    hOut[i] = o;
}

// -------- head at node level: y[n][0..9] = Hb[n][0..255] . W (W in LDS, broadcast) ----
__global__ __launch_bounds__(256) void head_y(const unsigned short* __restrict__ Hb,
        const float* __restrict__ W, float* __restrict__ y) {
    __shared__ float sw[HID * NCLS];
    int tid = threadIdx.x;
    for (int i = tid; i < HID * NCLS; i += 256) sw[i] = W[i];
    __syncthreads();
    int n = blockIdx.x * 256 + tid;
    if (n >= N_NODES) return;
    const unsigned short* hp = Hb + (long)n * HID;
    float acc[NCLS] = {};
    for (int k0 = 0; k0 < HID; k0 += 8) {
        u8v h = *(const u8v*)(hp + k0);
#pragma unroll
        for (int q = 0; q < 8; ++q) {
            float hv = bf2f(h[q]);
            const float* wr = sw + (k0 + q) * NCLS;
#pragma unroll
            for (int c = 0; c < NCLS; ++c) acc[c] = fmaf(hv, wr[c], acc[c]);
        }
    }
    float* yp = y + (long)n * 16;
    *(float4*)(yp)      = (float4){acc[0], acc[1], acc[2], acc[3]};
    *(float4*)(yp + 4)  = (float4){acc[4], acc[5], acc[6], acc[7]};
    *(float4*)(yp + 8)  = (float4){acc[8], acc[9], 0.f, 0.f};
    *(float4*)(yp + 12) = (float4){0.f, 0.f, 0.f, 0.f};
}

// ---------------- gathers ----------------
// edge gather d=128 (avg degree 40): buffered loads, 4B/lane, scalar idx
__global__ __launch_bounds__(256) void gather_e128(const int* __restrict__ off,
        const int* __restrict__ idx, const unsigned short* __restrict__ Y,
        unsigned short* __restrict__ outh) {
    int lane = threadIdx.x & 63;
    int r = blockIdx.x * 4 + (threadIdx.x >> 6);
    int f0 = lane * 2;
    int s = off[r], e = off[r + 1];
    float a[8][2] = {};
    int j = s;
    for (; j + 16 <= e; j += 16) {
        u2v g[16];
#pragma unroll
        for (int u = 0; u < 16; ++u) {
            int iv = __builtin_amdgcn_readfirstlane(idx[j + u]);
            g[u] = *(const u2v*)(Y + (long)iv * FT_DIM + f0);
        }
#pragma unroll
        for (int u = 0; u < 16; ++u) {
            a[u & 7][0] += bf2f(g[u][0]);
            a[u & 7][1] += bf2f(g[u][1]);
        }
    }
    for (; j + 8 <= e; j += 8) {
        u2v g[8];
#pragma unroll
        for (int u = 0; u < 8; ++u) {
            int iv = __builtin_amdgcn_readfirstlane(idx[j + u]);
            g[u] = *(const u2v*)(Y + (long)iv * FT_DIM + f0);
        }
#pragma unroll
        for (int u = 0; u < 8; ++u) {
            a[u][0] += bf2f(g[u][0]);
            a[u][1] += bf2f(g[u][1]);
        }
    }
    for (; j < e; ++j) {
        int iv = __builtin_amdgcn_readfirstlane(idx[j]);
        u2v g = *(const u2v*)(Y + (long)iv * FT_DIM + f0);
        a[0][0] += bf2f(g[0]);
        a[0][1] += bf2f(g[1]);
    }
    float s0 = 0.f, s1 = 0.f;
#pragma unroll
    for (int u = 0; u < 8; ++u) { s0 += a[u][0]; s1 += a[u][1]; }
    *(u2v*)(outh + (long)r * FT_DIM + f0) = (u2v){f2bf(s0), f2bf(s1)};
}

// node gather d=128 (avg degree 10): 4 chains, writes blocked single plane
__global__ __launch_bounds__(256) void gather_n128_planes(const int* __restrict__ off,
        const int* __restrict__ idx, const unsigned short* __restrict__ Y,
        unsigned short* __restrict__ Ph) {
    int lane = threadIdx.x & 63;
    int r = blockIdx.x * 4 + (threadIdx.x >> 6);
    int f0 = lane * 2;
    int s = off[r], e = off[r + 1];
    float a[4][2] = {};
    int j = s;
    for (; j + 4 <= e; j += 4) {
#pragma unroll
        for (int u = 0; u < 4; ++u) {
            int iv = __builtin_amdgcn_readfirstlane(idx[j + u]);
            u2v g = *(const u2v*)(Y + (long)iv * FT_DIM + f0);
            a[u][0] += bf2f(g[0]);
            a[u][1] += bf2f(g[1]);
        }
    }
    for (; j < e; ++j) {
        int iv = __builtin_amdgcn_readfirstlane(idx[j]);
        u2v g = *(const u2v*)(Y + (long)iv * FT_DIM + f0);
        a[0][0] += bf2f(g[0]);
        a[0][1] += bf2f(g[1]);
    }
    float s0 = a[0][0] + a[1][0] + a[2][0] + a[3][0];
    float s1 = a[0][1] + a[1][1] + a[2][1] + a[3][1];
    *(u2v*)(Ph + ablk(r, f0, FT_DIM)) = (u2v){f2bf(s0), f2bf(s1)};
}

// edge gather, HALF of d=256 (128 features = 256B rows): 8B/lane, half-wave = one row,
// halves take even/odd edges of the SAME list (scalar idx). Writes Eb half. Working set
// halved (10.2 MB) vs full-row gather -> fewer L2 misses per pass.
template<int HALF>
__global__ __launch_bounds__(256) void gather_e256_half(const int* __restrict__ off,
        const int* __restrict__ idx, const unsigned short* __restrict__ Y,
        unsigned short* __restrict__ Eb) {
    int lane = threadIdx.x & 63;
    int r = blockIdx.x * 4 + (threadIdx.x >> 6);
    int hh = lane >> 5;
    int f0 = (lane & 31) * 4;
    const unsigned short* Yh = Y + HALF * 128;
    int s = off[r], e = off[r + 1];
    float A[4][4] = {};
    int j = s;
    for (; j + 32 <= e; j += 32) {
        u4v g[16];
#pragma unroll
        for (int u = 0; u < 16; ++u) {
            int i0 = __builtin_amdgcn_readfirstlane(idx[j + 2 * u]);
            int i1 = __builtin_amdgcn_readfirstlane(idx[j + 2 * u + 1]);
            int iv = hh ? i1 : i0;
            g[u] = *(const u4v*)(Yh + (long)iv * HID + f0);
        }
#pragma unroll
        for (int u = 0; u < 16; ++u)
#pragma unroll
            for (int v = 0; v < 4; ++v) A[u & 3][v] += bf2f(g[u][v]);
    }
    for (; j + 16 <= e; j += 16) {
        u4v g[8];
#pragma unroll
        for (int u = 0; u < 8; ++u) {
            int i0 = __builtin_amdgcn_readfirstlane(idx[j + 2 * u]);
            int i1 = __builtin_amdgcn_readfirstlane(idx[j + 2 * u + 1]);
            int iv = hh ? i1 : i0;
            g[u] = *(const u4v*)(Yh + (long)iv * HID + f0);
        }
#pragma unroll
        for (int u = 0; u < 8; ++u)
#pragma unroll
            for (int v = 0; v < 4; ++v) A[u & 3][v] += bf2f(g[u][v]);
    }
    for (; j < e; j += 2) {
        int has1 = (j + 1 < e);
        int i0 = __builtin_amdgcn_readfirstlane(idx[j]);
        int i1 = __builtin_amdgcn_readfirstlane(idx[has1 ? j + 1 : j]);
        int iv = hh ? i1 : i0;
        u4v g = *(const u4v*)(Yh + (long)iv * HID + f0);
        if (!hh || has1) {
#pragma unroll
            for (int v = 0; v < 4; ++v) A[0][v] += bf2f(g[v]);
        }
    }
    u4v o;
#pragma unroll
    for (int v = 0; v < 4; ++v) {
        float sum = A[0][v] + A[1][v] + A[2][v] + A[3][v];
        sum += __shfl_xor(sum, 32, 64);
        o[v] = f2bf(sum);
    }
    if (hh == 0) *(u4v*)(Eb + (long)r * HID + HALF * 128 + f0) = o;
}

// node gather d=256 (avg degree 10): 16B/lane half-pair, writes blocked single plane
__global__ __launch_bounds__(256) void gather_n256_planes(const int* __restrict__ off,
        const int* __restrict__ idx, const unsigned short* __restrict__ Y,
        unsigned short* __restrict__ Ph) {
    int lane = threadIdx.x & 63;
    int r = blockIdx.x * 4 + (threadIdx.x >> 6);
    int hh = lane >> 5;
    int f0 = (lane & 31) * 8;
    int s = off[r], e = off[r + 1];
    float A[2][8] = {};
    int j = s;
    for (; j + 8 <= e; j += 8) {
        u8v g[4];
#pragma unroll
        for (int u = 0; u < 4; ++u) {
            int i0 = __builtin_amdgcn_readfirstlane(idx[j + 2 * u]);
            int i1 = __builtin_amdgcn_readfirstlane(idx[j + 2 * u + 1]);
            int iv = hh ? i1 : i0;
            g[u] = *(const u8v*)(Y + (long)iv * HID + f0);
        }
#pragma unroll
        for (int u = 0; u < 4; ++u)
#pragma unroll
            for (int v = 0; v < 8; ++v) A[u & 1][v] += bf2f(g[u][v]);
    }
    for (; j < e; j += 2) {
        int has1 = (j + 1 < e);
        int i0 = __builtin_amdgcn_readfirstlane(idx[j]);
        int i1 = __builtin_amdgcn_readfirstlane(idx[has1 ? j + 1 : j]);
        int iv = hh ? i1 : i0;
        u8v g = *(const u8v*)(Y + (long)iv * HID + f0);
        if (!hh || has1) {
#pragma unroll
            for (int v = 0; v < 8; ++v) A[0][v] += bf2f(g[v]);
        }
    }
    s8v o;
#pragma unroll
    for (int v = 0; v < 8; ++v) {
        float sum = A[0][v] + A[1][v];
        sum += __shfl_xor(sum, 32, 64);
        o[v] = (short)f2bf(sum);
    }
    if (hh == 0) *(s8v*)(Ph + ablk(r, f0, HID)) = o;
}

// edge sum over y rows (64B each): z[e] = sum_{n in e} y[n]. 4 threads/edge, float4.
__global__ __launch_bounds__(256) void gather_e_y(const int* __restrict__ off,
        const int* __restrict__ idx, const float* __restrict__ y,
        float* __restrict__ z) {
    int tid = threadIdx.x;
    int t = tid & 3;
    int e_ = blockIdx.x * 64 + (tid >> 2);
    if (e_ >= M_EDGES) return;
    int s = off[e_], e = off[e_ + 1];
    float4 a0 = {0,0,0,0}, a1 = {0,0,0,0}, a2 = {0,0,0,0}, a3 = {0,0,0,0};
    int j = s;
    for (; j + 4 <= e; j += 4) {
        float4 g0 = *(const float4*)(y + (long)idx[j] * 16 + t * 4);
        float4 g1 = *(const float4*)(y + (long)idx[j + 1] * 16 + t * 4);
        float4 g2 = *(const float4*)(y + (long)idx[j + 2] * 16 + t * 4);
        float4 g3 = *(const float4*)(y + (long)idx[j + 3] * 16 + t * 4);
        a0.x += g0.x; a0.y += g0.y; a0.z += g0.z; a0.w += g0.w;
        a1.x += g1.x; a1.y += g1.y; a1.z += g1.z; a1.w += g1.w;
        a2.x += g2.x; a2.y += g2.y; a2.z += g2.z; a2.w += g2.w;
        a3.x += g3.x; a3.y += g3.y; a3.z += g3.z; a3.w += g3.w;
    }
    for (; j < e; ++j) {
        float4 g0 = *(const float4*)(y + (long)idx[j] * 16 + t * 4);
        a0.x += g0.x; a0.y += g0.y; a0.z += g0.z; a0.w += g0.w;
    }
    float4 acc;
    acc.x = a0.x + a1.x + a2.x + a3.x;
    acc.y = a0.y + a1.y + a2.y + a3.y;
    acc.z = a0.z + a1.z + a2.z + a3.z;
    acc.w = a0.w + a1.w + a2.w + a3.w;
    *(float4*)(z + (long)e_ * 16 + t * 4) = acc;
}

// node readout over z rows (64B each): 4 threads per node, float4 per thread.
template<bool FIRST>
__global__ __launch_bounds__(256) void gather_z(const int* __restrict__ off,
        const int* __restrict__ idx, const float* __restrict__ z,
        const float* __restrict__ dinv, const float* __restrict__ hb,
        float* __restrict__ on) {
    int tid = threadIdx.x;
    int t = tid & 3;
    int n = blockIdx.x * 64 + (tid >> 2);
    int s = off[n], e = off[n + 1];
    float4 a0 = {0,0,0,0}, a1 = {0,0,0,0}, a2 = {0,0,0,0}, a3 = {0,0,0,0};
    int j = s;
    for (; j + 4 <= e; j += 4) {
        float4 g0 = *(const float4*)(z + (long)idx[j] * 16 + t * 4);
        float4 g1 = *(const float4*)(z + (long)idx[j + 1] * 16 + t * 4);
        float4 g2 = *(const float4*)(z + (long)idx[j + 2] * 16 + t * 4);
        float4 g3 = *(const float4*)(z + (long)idx[j + 3] * 16 + t * 4);
        a0.x += g0.x; a0.y += g0.y; a0.z += g0.z; a0.w += g0.w;
        a1.x += g1.x; a1.y += g1.y; a1.z += g1.z; a1.w += g1.w;
        a2.x += g2.x; a2.y += g2.y; a2.z += g2.z; a2.w += g2.w;
        a3.x += g3.x; a3.y += g3.y; a3.z += g3.z; a3.w += g3.w;
    }
    for (; j < e; ++j) {
        float4 g0 = *(const float4*)(z + (long)idx[j] * 16 + t * 4);
        a0.x += g0.x; a0.y += g0.y; a0.z += g0.z; a0.w += g0.w;
    }
    float di = dinv[n];
    float4 acc;
    acc.x = (a0.x + a1.x + a2.x + a3.x) * di;
    acc.y = (a0.y + a1.y + a2.y + a3.y) * di;
    acc.z = (a0.z + a1.z + a2.z + a3.z) * di;
    acc.w = (a0.w + a1.w + a2.w + a3.w) * di;
    float* op = on + (long)n * 16 + t * 4;
    if (FIRST) {
        float4 b;
#pragma unroll
        for (int k = 0; k < 4; ++k) {
            int c = t * 4 + k;
            ((float*)&b)[k] = (c < NCLS) ? hb[c] : 0.f;
        }
        *(float4*)op = (float4){acc.x + b.x, acc.y + b.y, acc.z + b.z, acc.w + b.w};
    } else {
        float4 old = *(float4*)op;
        *(float4*)op = (float4){old.x + acc.x, old.y + acc.y, old.z + acc.z, old.w + acc.w};
    }
}

// ---------------- single-A-plane MFMA GEMM, 128x128 tile, bf16 output ----------------
template<int K>
__global__ __launch_bounds__(256) void gemm128(const unsigned short* __restrict__ Ahg,
        const unsigned short* __restrict__ Bhg, const unsigned short* __restrict__ Blg,
        const float* __restrict__ bias, unsigned short* __restrict__ C,
        float* __restrict__ stats) {
    constexpr int KQ = K >> 3;
    __shared__ __align__(16) unsigned short Asl[16 * 512];   // 16 KB
    __shared__ __align__(16) unsigned short Bsl[32 * 512];   // 32 KB
    float* lsum = (float*)Asl;
    float* lsq  = lsum + 128;
    int tid = threadIdx.x;
    int lane = tid & 63, w = tid >> 6;
    int bx = blockIdx.x;
    int col0 = blockIdx.y * 128;
    int colblk0 = blockIdx.y * 2;
    int lm = lane & 15, lq = lane >> 4;
    int rbw = w >> 1;
    int rw = (w & 1) * 32;
    f4v acc[2][8];
#pragma unroll
    for (int i = 0; i < 2; ++i)
#pragma unroll
        for (int j = 0; j < 8; ++j) acc[i][j] = (f4v){0.f, 0.f, 0.f, 0.f};

    for (int ks = 0; ks < K / 64; ++ks) {
        int kq0 = ks * 8;
#pragma unroll
        for (int t = 0; t < 4; ++t) {
            int a = w * 4 + t;
            int rb = a >> 3, kqo = a & 7;
            const unsigned short* g = Ahg
                + ((long)((bx * 2 + rb) * KQ + kq0 + kqo) * 64 + lane) * 8;
            __builtin_amdgcn_global_load_lds(
                (const __attribute__((address_space(1))) void*)g,
                (__attribute__((address_space(3))) void*)(Asl + a * 512), 16, 0, 0);
        }
#pragma unroll
        for (int u = 0; u < 8; ++u) {
            int b = w * 8 + u;
            const unsigned short* g = ((b >> 4) ? Blg : Bhg)
                + ((long)((colblk0 + ((b >> 3) & 1)) * KQ + kq0 + (b & 7)) * 64 + lane) * 8;
            __builtin_amdgcn_global_load_lds(
                (const __attribute__((address_space(1))) void*)g,
                (__attribute__((address_space(3))) void*)(Bsl + b * 512), 16, 0, 0);
        }
        __syncthreads();
#pragma unroll
        for (int kk = 0; kk < 2; ++kk) {
            s8v ah[2];
#pragma unroll
            for (int i = 0; i < 2; ++i)
                ah[i] = *(const s8v*)&Asl[(rbw * 8 + kk * 4 + lq) * 512
                                          + (rw + i * 16 + lm) * 8];
#pragma unroll
            for (int j = 0; j < 8; ++j) {
                int cb = j >> 2;
                int c64 = (j & 3) * 16 + lm;
                s8v bh = *(const s8v*)&Bsl[(cb * 8 + kk * 4 + lq) * 512 + c64 * 8];
                s8v bl = *(const s8v*)&Bsl[(16 + cb * 8 + kk * 4 + lq) * 512 + c64 * 8];
#pragma unroll
                for (int i = 0; i < 2; ++i) {
                    acc[i][j] = __builtin_amdgcn_mfma_f32_16x16x32_bf16(ah[i], bl, acc[i][j], 0, 0, 0);
                    acc[i][j] = __builtin_amdgcn_mfma_f32_16x16x32_bf16(ah[i], bh, acc[i][j], 0, 0, 0);
                }
            }
        }
        __syncthreads();
    }
    if (tid < 128) { lsum[tid] = 0.f; lsq[tid] = 0.f; }
    __syncthreads();
#pragma unroll
    for (int j = 0; j < 8; ++j) {
        int lc = j * 16 + lm;
        int col = col0 + lc;
        float bsv = bias[col];
        float s = 0.f, sq = 0.f;
#pragma unroll
        for (int i = 0; i < 2; ++i) {
#pragma unroll
            for (int reg = 0; reg < 4; ++reg) {
                long row = (long)bx * 128 + rbw * 64 + rw + i * 16 + lq * 4 + reg;
                if (row < N_NODES) {
                    unsigned short hv = f2bf(acc[i][j][reg] + bsv);
                    float vr = bf2f(hv);
                    C[row * HID + col] = hv;
                    s += vr;
                    sq += vr * vr;
                }
            }
        }
        atomicAdd(&lsum[lc], s);
        atomicAdd(&lsq[lc], sq);
    }
    __syncthreads();
    if (tid < 128) {
        atomicAdd(&stats[col0 + tid], lsum[tid]);
        atomicAdd(&stats[HID + col0 + tid], lsq[tid]);
    }
}

// ---------------- readout (onodes stride 16) ----------------
__global__ __launch_bounds__(256) void readout_accum(const float* __restrict__ on,
                                                     const int* __restrict__ ab,
                                                     float* __restrict__ racc,
                                                     float* __restrict__ rcnt) {
    __shared__ float lacc[NG * NCLS];
    __shared__ float lcnt[NG];
    int tid = threadIdx.x;
    for (int i = tid; i < NG * NCLS; i += 256) lacc[i] = 0.f;
    if (tid < NG) lcnt[tid] = 0.f;
    __syncthreads();
    int n = blockIdx.x * 256 + tid;
    if (n < N_NODES) {
        int b = ab[n];
        atomicAdd(&lcnt[b], 1.0f);
        for (int c = 0; c < NCLS; ++c) atomicAdd(&lacc[b * NCLS + c], on[(long)n * 16 + c]);
    }
    __syncthreads();
    if (tid < NG && lcnt[tid] > 0.f) {
        atomicAdd(&rcnt[tid], lcnt[tid]);
        for (int c = 0; c < NCLS; ++c) atomicAdd(&racc[tid * NCLS + c], lacc[tid * NCLS + c]);
    }
}

__global__ void readout_final(const float* __restrict__ racc, const float* __restrict__ rcnt,
                              float* __restrict__ out) {
    int i = blockIdx.x * 256 + threadIdx.x;
    if (i < NG * NCLS) out[i] = racc[i] / fmaxf(rcnt[i / NCLS], 1.0f);
}

// ---------------- launch ----------------
extern "C" void kernel_launch(void* const* d_in, const int* in_sizes, int n_in,
                              void* d_out, int out_size, void* d_ws, size_t ws_size,
                              hipStream_t stream) {
    const float* X         = (const float*)d_in[0];
    const int*   node_idx  = (const int*)d_in[1];
    const int*   edge_idx  = (const int*)d_in[2];
    const int*   all_batch = (const int*)d_in[3];
    const float* W1[2]  = {(const float*)d_in[4],  (const float*)d_in[12]};
    const float* b1[2]  = {(const float*)d_in[5],  (const float*)d_in[13]};
    const float* g1[2]  = {(const float*)d_in[6],  (const float*)d_in[14]};
    const float* be1[2] = {(const float*)d_in[7],  (const float*)d_in[15]};
    const float* W2[2]  = {(const float*)d_in[8],  (const float*)d_in[16]};
    const float* b2[2]  = {(const float*)d_in[9],  (const float*)d_in[17]};
    const float* bng[2] = {(const float*)d_in[10], (const float*)d_in[18]};
    const float* bnb[2] = {(const float*)d_in[11], (const float*)d_in[19]};
    const float* headW  = (const float*)d_in[20];
    const float* headb  = (const float*)d_in[21];
    float* out = (float*)d_out;

    char* base = (char*)d_ws;
    size_t off = 0;
    auto alloc = [&](size_t bytes) -> void* {
        size_t o = (off + 255) & ~(size_t)255;
        off = o + bytes;
        return (void*)(base + o);
    };

    const int ZINTS = M_EDGES + N_NODES;
    const int ZTOT  = ZINTS + 4 * 2 * HID + NG * NCLS + NG;
    int* ibase  = (int*)alloc((size_t)ZTOT * 4);
    int* cnt_e  = ibase;
    int* cnt_n  = cnt_e + M_EDGES;
    float* statsall = (float*)(ibase + ZINTS);
    float* racc     = statsall + 4 * 2 * HID;
    float* rcnt     = racc + NG * NCLS;

    int* off_e  = (int*)alloc((M_EDGES + 1) * 4);
    int* off_n  = (int*)alloc((N_NODES + 1) * 4);
    int* gcur_e = (int*)alloc(NBE * 4);
    int* gcur_n = (int*)alloc(NBN * 4);
    int* idx_e  = (int*)alloc((size_t)NNZ_CNT * 4);
    int* idx_n  = (int*)alloc((size_t)NNZ_CNT * 4);
    unsigned* stg_e = (unsigned*)alloc((size_t)NNZ_CNT * 4);
    unsigned* stg_n = (unsigned*)alloc((size_t)NNZ_CNT * 4);
    float* dinv = (float*)alloc((size_t)N_NODES * 4);

    unsigned short* Xb = (unsigned short*)alloc((size_t)N_NODES * FT_DIM * 2);
    unsigned short* Eb = (unsigned short*)alloc((size_t)M_EDGES * HID * 2);
    unsigned short* Ph = (unsigned short*)alloc((size_t)M_PAD * HID * 2);
    unsigned short* Ahp = (unsigned short*)alloc((size_t)M_PAD * HID * 2);
    unsigned short* Hb  = (unsigned short*)alloc((size_t)N_NODES * HID * 2);
    unsigned short* Tb  = (unsigned short*)alloc((size_t)N_NODES * HID * 2);
    float* onodes = (float*)alloc((size_t)N_NODES * 16 * 4);
    float* ybuf   = (float*)alloc((size_t)N_NODES * 16 * 4);
    float* zbuf   = (float*)alloc((size_t)M_EDGES * 16 * 4);
    unsigned short* Wp[4][2];
    int WK[4] = {FT_DIM, HID, HID, HID};
    for (int m = 0; m < 4; ++m) {
        Wp[m][0] = (unsigned short*)alloc((size_t)WK[m] * HID * 2);
        Wp[m][1] = (unsigned short*)alloc((size_t)WK[m] * HID * 2);
    }

    const int nnz_blocks = (NNZ_CNT + 255) / 256;
    const int n8 = N_NODES * HID / 8;
    const dim3 ggrid(M_PAD / 128, 2);

    // --- CSR build (bucketed counting sort) + degree norm + weight prep ---
    fzero<<<(ZTOT + 255) / 256, 256, 0, stream>>>((float*)ibase, ZTOT);
    count_kernel<<<nnz_blocks, 256, 0, stream>>>(node_idx, edge_idx, cnt_e, cnt_n);
    exscan2<<<2, 1024, 0, stream>>>(cnt_e, off_e, cnt_n, off_n, gcur_e, gcur_n);
    partition_kernel<<<(NNZ_CNT + 8191) / 8192, 256, 0, stream>>>(node_idx, edge_idx,
                                                                  gcur_e, gcur_n, stg_e, stg_n);
    bucket_fill<<<NBE + NBN, 256, 0, stream>>>(off_e, off_n, stg_e, stg_n, idx_e, idx_n);
    dinv_kernel<<<(N_NODES + 255) / 256, 256, 0, stream>>>(off_n, idx_n, cnt_e, dinv);
    WPA wpa;
    wpa.W[0] = W1[0]; wpa.W[1] = W2[0]; wpa.W[2] = W1[1]; wpa.W[3] = W2[1];
    for (int m = 0; m < 4; ++m) { wpa.h[m] = Wp[m][0]; wpa.l[m] = Wp[m][1]; }
    wprep_all<<<dim3(256, 4), 256, 0, stream>>>(wpa);
    fsplit<<<(N_NODES * FT_DIM / 4 + 255) / 256, 256, 0, stream>>>((const float4*)X,
                                                                   (u4v*)Xb, N_NODES * FT_DIM / 4);

    // ---------------- layer 0 ----------------
    gather_e128<<<M_EDGES / 4, 256, 0, stream>>>(off_e, idx_e, Xb, Eb);
    gather_n128_planes<<<N_NODES / 4, 256, 0, stream>>>(off_n, idx_n, Eb, Ph);
    gemm128<FT_DIM><<<ggrid, 256, 0, stream>>>(Ph, Wp[0][0], Wp[0][1], b1[0], Tb,
                                               statsall + 0 * 512);
    bn_split_blk<<<N_NODES / 64, 256, 0, stream>>>(Tb, statsall + 0 * 512, g1[0], be1[0], Ahp);
    gemm128<HID><<<ggrid, 256, 0, stream>>>(Ahp, Wp[1][0], Wp[1][1], b2[0], Tb,
                                            statsall + 1 * 512);
    bn_rowmajor<<<(n8 + 255) / 256, 256, 0, stream>>>((const u8v*)Tb, statsall + 1 * 512,
                                                      bng[0], bnb[0], (u8v*)Hb, n8);
    // readout head at node level + Eb pooling (two half-feature passes)
    head_y<<<(N_NODES + 255) / 256, 256, 0, stream>>>(Hb, headW, ybuf);
    gather_e256_half<0><<<M_EDGES / 4, 256, 0, stream>>>(off_e, idx_e, Hb, Eb);
    gather_e256_half<1><<<M_EDGES / 4, 256, 0, stream>>>(off_e, idx_e, Hb, Eb);
    gather_e_y<<<(M_EDGES + 63) / 64, 256, 0, stream>>>(off_e, idx_e, ybuf, zbuf);
    gather_z<true><<<N_NODES / 64, 256, 0, stream>>>(off_n, idx_n, zbuf, dinv, headb, onodes);
    gather_n256_planes<<<N_NODES / 4, 256, 0, stream>>>(off_n, idx_n, Eb, Ph);

    // ---------------- layer 1 ----------------
    gemm128<HID><<<ggrid, 256, 0, stream>>>(Ph, Wp[2][0], Wp[2][1], b1[1], Tb,
                                            statsall + 2 * 512);
    bn_split_blk<<<N_NODES / 64, 256, 0, stream>>>(Tb, statsall + 2 * 512, g1[1], be1[1], Ahp);
    gemm128<HID><<<ggrid, 256, 0, stream>>>(Ahp, Wp[3][0], Wp[3][1], b2[1], Tb,
                                            statsall + 3 * 512);
    bn_rowmajor<<<(n8 + 255) / 256, 256, 0, stream>>>((const u8v*)Tb, statsall + 3 * 512,
                                                      bng[1], bnb[1], (u8v*)Hb, n8);
    // layer-1 readout: entirely via y-path (no full-width edge gather needed)
    head_y<<<(N_NODES + 255) / 256, 256, 0, stream>>>(Hb, headW + (size_t)HID * NCLS, ybuf);
    gather_e_y<<<(M_EDGES + 63) / 64, 256, 0, stream>>>(off_e, idx_e, ybuf, zbuf);
    gather_z<false><<<N_NODES / 64, 256, 0, stream>>>(off_n, idx_n, zbuf, dinv, nullptr, onodes);

    // ---------------- readout ----------------
    readout_accum<<<(N_NODES + 255) / 256, 256, 0, stream>>>(onodes, all_batch, racc, rcnt);
    readout_final<<<(NG * NCLS + 255) / 256, 256, 0, stream>>>(racc, rcnt, out);
}

// Round 13
// 559.181 us; speedup vs baseline: 1.0256x; 1.0256x over previous
//
#include <hip/hip_runtime.h>

#define N_NODES 40000
#define M_PAD   40064          // 313 * 128
#define M_EDGES 10000
#define NNZ_CNT 400000
#define FT_DIM  128
#define HID     256
#define NCLS    10
#define NG      128
#define EPSV    1e-5f
#define ROWSINV (1.0f / 40000.0f)

#define NBE 79    // edge buckets: key >> 7 (128 keys each)
#define NBN 157   // node buckets: key >> 8 (256 keys each)

typedef short s8v __attribute__((ext_vector_type(8)));
typedef unsigned short u8v __attribute__((ext_vector_type(8)));
typedef float f4v __attribute__((ext_vector_type(4)));
typedef unsigned short u4v __attribute__((ext_vector_type(4)));
typedef unsigned short u2v __attribute__((ext_vector_type(2)));

__device__ __forceinline__ unsigned short f2bf(float x) {
    unsigned int u = __float_as_uint(x);
    u += 0x7fffu + ((u >> 16) & 1u);
    return (unsigned short)(u >> 16);
}
__device__ __forceinline__ float bf2f(unsigned short h) {
    return __uint_as_float(((unsigned int)h) << 16);
}

// blocked-chunk element address (in shorts) for (r, k): layout [r/64][k/8][r%64] 16B chunks
__device__ __forceinline__ long ablk(int r, int k, int K) {
    return ((long)((r >> 6) * (K >> 3) + (k >> 3)) * 64 + (r & 63)) * 8 + (k & 7);
}

// ---------------- utility ----------------
__global__ void fzero(float* __restrict__ p, int n) {
    int i = blockIdx.x * 256 + threadIdx.x;
    if (i < n) p[i] = 0.f;
}

// ---------------- CSR build ----------------
__global__ void count_kernel(const int* __restrict__ ni, const int* __restrict__ ei,
                             int* __restrict__ cnt_e, int* __restrict__ cnt_n) {
    int i = blockIdx.x * 256 + threadIdx.x;
    if (i < NNZ_CNT) {
        atomicAdd(&cnt_e[ei[i]], 1);
        atomicAdd(&cnt_n[ni[i]], 1);
    }
}

__device__ void exscan_body(const int* __restrict__ in, int* __restrict__ out, int n) {
    __shared__ int wsum[16];
    __shared__ int carry_s;
    int tid = threadIdx.x, lane = tid & 63, w = tid >> 6;
    if (tid == 0) carry_s = 0;
    __syncthreads();
    for (int base = 0; base < n; base += 4096) {
        int i0 = base + tid * 4;
        int v[4];
#pragma unroll
        for (int t = 0; t < 4; ++t) v[t] = (i0 + t < n) ? in[i0 + t] : 0;
        int s = v[0] + v[1] + v[2] + v[3];
        int sc = s;
#pragma unroll
        for (int d = 1; d < 64; d <<= 1) {
            int t = __shfl_up(sc, d, 64);
            if (lane >= d) sc += t;
        }
        if (lane == 63) wsum[w] = sc;
        __syncthreads();
        if (tid < 64) {
            int ws = (lane < 16) ? wsum[lane] : 0;
            int wsc = ws;
#pragma unroll
            for (int d = 1; d < 16; d <<= 1) {
                int t = __shfl_up(wsc, d, 64);
                if (lane >= d) wsc += t;
            }
            if (lane < 16) wsum[lane] = wsc - ws;
        }
        __syncthreads();
        int carry = carry_s;
        int ex = carry + wsum[w] + (sc - s);
#pragma unroll
        for (int t = 0; t < 4; ++t) {
            if (i0 + t < n) out[i0 + t] = ex;
            ex += v[t];
        }
        __syncthreads();
        if (tid == 1023) carry_s = ex;
    }
    __syncthreads();
    if (tid == 0) out[n] = carry_s;
}

__global__ __launch_bounds__(1024) void exscan2(const int* __restrict__ ce, int* __restrict__ oe,
                                                const int* __restrict__ cn, int* __restrict__ on_,
                                                int* __restrict__ gcur_e, int* __restrict__ gcur_n) {
    int tid = threadIdx.x;
    if (blockIdx.x == 0) {
        exscan_body(ce, oe, M_EDGES);
        __syncthreads();
        for (int b = tid; b < NBE; b += 1024) gcur_e[b] = oe[b << 7];
    } else {
        exscan_body(cn, on_, N_NODES);
        __syncthreads();
        for (int b = tid; b < NBN; b += 1024) gcur_n[b] = on_[b << 8];
    }
}

// ---- partition: LDS multisplit by bucket, run-burst append into staging ----
template<int NB, int SH, bool EDGE>
__device__ void part_side(const int* __restrict__ key, const int* __restrict__ val,
                          int* __restrict__ gcur, unsigned* __restrict__ stg,
                          unsigned* buf, int* hist, int* loff, int* lcur, int* gbase,
                          int i0, int items) {
    int tid = threadIdx.x;
    for (int b = tid; b < NB; b += 256) hist[b] = 0;
    __syncthreads();
    for (int p = tid; p < items; p += 256) atomicAdd(&hist[key[i0 + p] >> SH], 1);
    __syncthreads();
    if (tid == 0) {
        int s = 0;
        for (int b = 0; b < NB; ++b) { loff[b] = s; s += hist[b]; }
    }
    __syncthreads();
    for (int b = tid; b < NB; b += 256) lcur[b] = loff[b];
    __syncthreads();
    for (int p = tid; p < items; p += 256) {
        int k = key[i0 + p], v = val[i0 + p];
        int pos = atomicAdd(&lcur[k >> SH], 1);
        buf[pos] = EDGE ? (((unsigned)k << 16) | (unsigned)v)
                        : (((unsigned)k << 14) | (unsigned)v);
    }
    __syncthreads();
    for (int b = tid; b < NB; b += 256) gbase[b] = atomicAdd(&gcur[b], hist[b]);
    __syncthreads();
    for (int p = tid; p < items; p += 256) {
        unsigned en = buf[p];
        int k = EDGE ? (int)(en >> 16) : (int)(en >> 14);
        int b = k >> SH;
        stg[gbase[b] + (p - loff[b])] = en;
    }
    __syncthreads();
}

__global__ __launch_bounds__(256) void partition_kernel(const int* __restrict__ ni,
        const int* __restrict__ ei, int* __restrict__ gcur_e, int* __restrict__ gcur_n,
        unsigned* __restrict__ stg_e, unsigned* __restrict__ stg_n) {
    __shared__ unsigned buf[8192];
    __shared__ int hist[160], loff[160], lcur[160], gbase[160];
    int i0 = blockIdx.x * 8192;
    int items = NNZ_CNT - i0;
    if (items > 8192) items = 8192;
    part_side<NBE, 7, true>(ei, ni, gcur_e, stg_e, buf, hist, loff, lcur, gbase, i0, items);
    part_side<NBN, 8, false>(ni, ei, gcur_n, stg_n, buf, hist, loff, lcur, gbase, i0, items);
}

__global__ __launch_bounds__(256) void bucket_fill(const int* __restrict__ off_e,
        const int* __restrict__ off_n, const unsigned* __restrict__ stg_e,
        const unsigned* __restrict__ stg_n, int* __restrict__ idx_e,
        int* __restrict__ idx_n) {
    __shared__ int cur[257];
    int tid = threadIdx.x;
    int b = blockIdx.x;
    if (b < NBE) {
        int k0 = b << 7, k1 = min(k0 + 128, M_EDGES), nk = k1 - k0;
        int base = off_e[k0];
        for (int i = tid; i <= nk; i += 256) cur[i] = off_e[k0 + i] - base;
        __syncthreads();
        int cnt = cur[nk];
        for (int p = tid; p < cnt; p += 256) {
            unsigned en = stg_e[base + p];
            int loc = atomicAdd(&cur[(int)(en >> 16) - k0], 1);
            idx_e[base + loc] = (int)(en & 0xFFFFu);
        }
    } else {
        b -= NBE;
        int k0 = b << 8, k1 = min(k0 + 256, N_NODES), nk = k1 - k0;
        int base = off_n[k0];
        for (int i = tid; i <= nk; i += 256) cur[i] = off_n[k0 + i] - base;
        __syncthreads();
        int cnt = cur[nk];
        for (int p = tid; p < cnt; p += 256) {
            unsigned en = stg_n[base + p];
            int loc = atomicAdd(&cur[(int)(en >> 14) - k0], 1);
            idx_n[base + loc] = (int)(en & 0x3FFFu);
        }
    }
}

__global__ void dinv_kernel(const int* __restrict__ off_n, const int* __restrict__ idx_n,
                            const int* __restrict__ cnt_e, float* __restrict__ dinv) {
    int n = blockIdx.x * 256 + threadIdx.x;
    if (n < N_NODES) {
        int s = off_n[n], e = off_n[n + 1];
        float p = 0.f;
        for (int j = s; j < e; ++j) p += (float)cnt_e[idx_n[j]];
        dinv[n] = (p > 0.f) ? 1.0f / p : 1.0f;
    }
}

// -------- weight prep (all 4 mats): W[K x 256] fp32 -> blocked hi/lo planes --------
struct WPA {
    const float* W[4];
    unsigned short* h[4];
    unsigned short* l[4];
};
__global__ void wprep_all(WPA p) {
    int m = blockIdx.y;
    int K = (m == 0) ? FT_DIM : HID;
    int i = blockIdx.x * 256 + threadIdx.x;
    if (i >= K * 256) return;
    int k = i >> 8, c = i & 255;
    float x = p.W[m][i];
    unsigned short hh = f2bf(x);
    long o = ((long)((c >> 6) * (K >> 3) + (k >> 3)) * 64 + (c & 63)) * 8 + (k & 7);
    p.h[m][o] = hh;
    p.l[m][o] = f2bf(x - bf2f(hh));
}

// ---------------- fp32 -> bf16 (round only, row-major) ----------------
__global__ void fsplit(const float4* __restrict__ src, u4v* __restrict__ h, int n4) {
    int i = blockIdx.x * 256 + threadIdx.x;
    if (i < n4) {
        float4 v = src[i];
        h[i] = (u4v){f2bf(v.x), f2bf(v.y), f2bf(v.z), f2bf(v.w)};
    }
}

// -------- relu(bn(x)) on bf16 src -> blocked single bf16 plane, BN finalize fused --------
__global__ __launch_bounds__(256) void bn_split_blk(const unsigned short* __restrict__ src,
        const float* __restrict__ stats, const float* __restrict__ g,
        const float* __restrict__ be, unsigned short* __restrict__ hOut) {
    __shared__ float sa[HID], sc_[HID];
    int tid = threadIdx.x;
    {
        float mean = stats[tid] * ROWSINV;
        float var = stats[HID + tid] * ROWSINV - mean * mean;
        float av = g[tid] * rsqrtf(var + EPSV);
        sa[tid] = av;
        sc_[tid] = be[tid] - mean * av;
    }
    __syncthreads();
    int r = tid >> 2, kqg = tid & 3;
    long row = (long)blockIdx.x * 64 + r;
    long cbase = ((long)blockIdx.x * 32) * 64 + r;
#pragma unroll
    for (int t = 0; t < 8; ++t) {
        int kq = kqg * 8 + t;
        u8v v = *(const u8v*)(src + row * HID + kq * 8);
        float4 a0 = *(const float4*)(sa + kq * 8);
        float4 a1 = *(const float4*)(sa + kq * 8 + 4);
        float4 c0 = *(const float4*)(sc_ + kq * 8);
        float4 c1 = *(const float4*)(sc_ + kq * 8 + 4);
        s8v h;
        h[0] = (short)f2bf(fmaxf(fmaf(a0.x, bf2f(v[0]), c0.x), 0.f));
        h[1] = (short)f2bf(fmaxf(fmaf(a0.y, bf2f(v[1]), c0.y), 0.f));
        h[2] = (short)f2bf(fmaxf(fmaf(a0.z, bf2f(v[2]), c0.z), 0.f));
        h[3] = (short)f2bf(fmaxf(fmaf(a0.w, bf2f(v[3]), c0.w), 0.f));
        h[4] = (short)f2bf(fmaxf(fmaf(a1.x, bf2f(v[4]), c1.x), 0.f));
        h[5] = (short)f2bf(fmaxf(fmaf(a1.y, bf2f(v[5]), c1.y), 0.f));
        h[6] = (short)f2bf(fmaxf(fmaf(a1.z, bf2f(v[6]), c1.z), 0.f));
        h[7] = (short)f2bf(fmaxf(fmaf(a1.w, bf2f(v[7]), c1.w), 0.f));
        *(s8v*)(hOut + (cbase + (long)kq * 64) * 8) = h;
    }
}

// -------- relu(bn(x)) on bf16 src -> row-major bf16, BN finalize fused --------
__global__ __launch_bounds__(256) void bn_rowmajor(const u8v* __restrict__ src,
        const float* __restrict__ stats, const float* __restrict__ g,
        const float* __restrict__ be, u8v* __restrict__ hOut, int n8) {
    __shared__ float sa[HID], sc_[HID];
    int tid = threadIdx.x;
    {
        float mean = stats[tid] * ROWSINV;
        float var = stats[HID + tid] * ROWSINV - mean * mean;
        float av = g[tid] * rsqrtf(var + EPSV);
        sa[tid] = av;
        sc_[tid] = be[tid] - mean * av;
    }
    __syncthreads();
    int i = blockIdx.x * 256 + tid;
    if (i >= n8) return;
    int col = (i << 3) & (HID - 1);
    u8v v = src[i];
    u8v o;
#pragma unroll
    for (int q = 0; q < 8; ++q)
        o[q] = f2bf(fmaxf(fmaf(sa[col + q], bf2f(v[q]), sc_[col + q]), 0.f));
    hOut[i] = o;
}

// -------- head at node level: y[n][0..9] = Hb[n][0..255] . W (W in LDS, broadcast) ----
__global__ __launch_bounds__(256) void head_y(const unsigned short* __restrict__ Hb,
        const float* __restrict__ W, float* __restrict__ y) {
    __shared__ float sw[HID * NCLS];
    int tid = threadIdx.x;
    for (int i = tid; i < HID * NCLS; i += 256) sw[i] = W[i];
    __syncthreads();
    int n = blockIdx.x * 256 + tid;
    if (n >= N_NODES) return;
    const unsigned short* hp = Hb + (long)n * HID;
    float acc[NCLS] = {};
    for (int k0 = 0; k0 < HID; k0 += 8) {
        u8v h = *(const u8v*)(hp + k0);
#pragma unroll
        for (int q = 0; q < 8; ++q) {
            float hv = bf2f(h[q]);
            const float* wr = sw + (k0 + q) * NCLS;
#pragma unroll
            for (int c = 0; c < NCLS; ++c) acc[c] = fmaf(hv, wr[c], acc[c]);
        }
    }
    float* yp = y + (long)n * 16;
    *(float4*)(yp)      = (float4){acc[0], acc[1], acc[2], acc[3]};
    *(float4*)(yp + 4)  = (float4){acc[4], acc[5], acc[6], acc[7]};
    *(float4*)(yp + 8)  = (float4){acc[8], acc[9], 0.f, 0.f};
    *(float4*)(yp + 12) = (float4){0.f, 0.f, 0.f, 0.f};
}

// ---------------- gathers ----------------
// edge gather d=128 (avg degree 40): buffered loads, 4B/lane, scalar idx
__global__ __launch_bounds__(256) void gather_e128(const int* __restrict__ off,
        const int* __restrict__ idx, const unsigned short* __restrict__ Y,
        unsigned short* __restrict__ outh) {
    int lane = threadIdx.x & 63;
    int r = blockIdx.x * 4 + (threadIdx.x >> 6);
    int f0 = lane * 2;
    int s = off[r], e = off[r + 1];
    float a[8][2] = {};
    int j = s;
    for (; j + 16 <= e; j += 16) {
        u2v g[16];
#pragma unroll
        for (int u = 0; u < 16; ++u) {
            int iv = __builtin_amdgcn_readfirstlane(idx[j + u]);
            g[u] = *(const u2v*)(Y + (long)iv * FT_DIM + f0);
        }
#pragma unroll
        for (int u = 0; u < 16; ++u) {
            a[u & 7][0] += bf2f(g[u][0]);
            a[u & 7][1] += bf2f(g[u][1]);
        }
    }
    for (; j + 8 <= e; j += 8) {
        u2v g[8];
#pragma unroll
        for (int u = 0; u < 8; ++u) {
            int iv = __builtin_amdgcn_readfirstlane(idx[j + u]);
            g[u] = *(const u2v*)(Y + (long)iv * FT_DIM + f0);
        }
#pragma unroll
        for (int u = 0; u < 8; ++u) {
            a[u][0] += bf2f(g[u][0]);
            a[u][1] += bf2f(g[u][1]);
        }
    }
    for (; j < e; ++j) {
        int iv = __builtin_amdgcn_readfirstlane(idx[j]);
        u2v g = *(const u2v*)(Y + (long)iv * FT_DIM + f0);
        a[0][0] += bf2f(g[0]);
        a[0][1] += bf2f(g[1]);
    }
    float s0 = 0.f, s1 = 0.f;
#pragma unroll
    for (int u = 0; u < 8; ++u) { s0 += a[u][0]; s1 += a[u][1]; }
    *(u2v*)(outh + (long)r * FT_DIM + f0) = (u2v){f2bf(s0), f2bf(s1)};
}

// node gather d=128 (avg degree 10): 4 chains, writes blocked single plane
__global__ __launch_bounds__(256) void gather_n128_planes(const int* __restrict__ off,
        const int* __restrict__ idx, const unsigned short* __restrict__ Y,
        unsigned short* __restrict__ Ph) {
    int lane = threadIdx.x & 63;
    int r = blockIdx.x * 4 + (threadIdx.x >> 6);
    int f0 = lane * 2;
    int s = off[r], e = off[r + 1];
    float a[4][2] = {};
    int j = s;
    for (; j + 4 <= e; j += 4) {
#pragma unroll
        for (int u = 0; u < 4; ++u) {
            int iv = __builtin_amdgcn_readfirstlane(idx[j + u]);
            u2v g = *(const u2v*)(Y + (long)iv * FT_DIM + f0);
            a[u][0] += bf2f(g[0]);
            a[u][1] += bf2f(g[1]);
        }
    }
    for (; j < e; ++j) {
        int iv = __builtin_amdgcn_readfirstlane(idx[j]);
        u2v g = *(const u2v*)(Y + (long)iv * FT_DIM + f0);
        a[0][0] += bf2f(g[0]);
        a[0][1] += bf2f(g[1]);
    }
    float s0 = a[0][0] + a[1][0] + a[2][0] + a[3][0];
    float s1 = a[0][1] + a[1][1] + a[2][1] + a[3][1];
    *(u2v*)(Ph + ablk(r, f0, FT_DIM)) = (u2v){f2bf(s0), f2bf(s1)};
}

// edge gather d=256 (full width, Eb only): 16B/lane, half-wave = one row; halves take
// even/odd edges of the SAME list (scalar idx). Round-11-proven structure.
__global__ __launch_bounds__(256) void gather_e256(const int* __restrict__ off,
        const int* __restrict__ idx, const unsigned short* __restrict__ Y,
        unsigned short* __restrict__ Eb) {
    int lane = threadIdx.x & 63;
    int r = blockIdx.x * 4 + (threadIdx.x >> 6);
    int hh = lane >> 5;
    int f0 = (lane & 31) * 8;
    int s = off[r], e = off[r + 1];
    float A[4][8] = {};
    int j = s;
    for (; j + 16 <= e; j += 16) {
        u8v g[8];
#pragma unroll
        for (int u = 0; u < 8; ++u) {
            int i0 = __builtin_amdgcn_readfirstlane(idx[j + 2 * u]);
            int i1 = __builtin_amdgcn_readfirstlane(idx[j + 2 * u + 1]);
            int iv = hh ? i1 : i0;
            g[u] = *(const u8v*)(Y + (long)iv * HID + f0);
        }
#pragma unroll
        for (int u = 0; u < 8; ++u)
#pragma unroll
            for (int v = 0; v < 8; ++v) A[u & 3][v] += bf2f(g[u][v]);
    }
    for (; j < e; j += 2) {
        int has1 = (j + 1 < e);
        int i0 = __builtin_amdgcn_readfirstlane(idx[j]);
        int i1 = __builtin_amdgcn_readfirstlane(idx[has1 ? j + 1 : j]);
        int iv = hh ? i1 : i0;
        u8v g = *(const u8v*)(Y + (long)iv * HID + f0);
        if (!hh || has1) {
#pragma unroll
            for (int v = 0; v < 8; ++v) A[0][v] += bf2f(g[v]);
        }
    }
    if (hh == 0) {
        u8v o;
#pragma unroll
        for (int v = 0; v < 8; ++v) {
            float sum = A[0][v] + A[1][v] + A[2][v] + A[3][v];
            sum += __shfl_xor(sum, 32, 64);
            o[v] = f2bf(sum);
        }
        *(u8v*)(Eb + (long)r * HID + f0) = o;
    } else {
        // participate in the shuffle (both halves execute the same shfl sequence)
#pragma unroll
        for (int v = 0; v < 8; ++v) {
            float sum = A[0][v] + A[1][v] + A[2][v] + A[3][v];
            sum += __shfl_xor(sum, 32, 64);
            (void)sum;
        }
    }
}

// node gather d=256 (avg degree 10): 16B/lane half-pair, writes blocked single plane
__global__ __launch_bounds__(256) void gather_n256_planes(const int* __restrict__ off,
        const int* __restrict__ idx, const unsigned short* __restrict__ Y,
        unsigned short* __restrict__ Ph) {
    int lane = threadIdx.x & 63;
    int r = blockIdx.x * 4 + (threadIdx.x >> 6);
    int hh = lane >> 5;
    int f0 = (lane & 31) * 8;
    int s = off[r], e = off[r + 1];
    float A[2][8] = {};
    int j = s;
    for (; j + 8 <= e; j += 8) {
        u8v g[4];
#pragma unroll
        for (int u = 0; u < 4; ++u) {
            int i0 = __builtin_amdgcn_readfirstlane(idx[j + 2 * u]);
            int i1 = __builtin_amdgcn_readfirstlane(idx[j + 2 * u + 1]);
            int iv = hh ? i1 : i0;
            g[u] = *(const u8v*)(Y + (long)iv * HID + f0);
        }
#pragma unroll
        for (int u = 0; u < 4; ++u)
#pragma unroll
            for (int v = 0; v < 8; ++v) A[u & 1][v] += bf2f(g[u][v]);
    }
    for (; j < e; j += 2) {
        int has1 = (j + 1 < e);
        int i0 = __builtin_amdgcn_readfirstlane(idx[j]);
        int i1 = __builtin_amdgcn_readfirstlane(idx[has1 ? j + 1 : j]);
        int iv = hh ? i1 : i0;
        u8v g = *(const u8v*)(Y + (long)iv * HID + f0);
        if (!hh || has1) {
#pragma unroll
            for (int v = 0; v < 8; ++v) A[0][v] += bf2f(g[v]);
        }
    }
    s8v o;
#pragma unroll
    for (int v = 0; v < 8; ++v) {
        float sum = A[0][v] + A[1][v];
        sum += __shfl_xor(sum, 32, 64);
        o[v] = (short)f2bf(sum);
    }
    if (hh == 0) *(s8v*)(Ph + ablk(r, f0, HID)) = o;
}

// edge sum over y rows (64B each): z[e] = sum_{n in e} y[n]. 4 threads/edge, float4.
__global__ __launch_bounds__(256) void gather_e_y(const int* __restrict__ off,
        const int* __restrict__ idx, const float* __restrict__ y,
        float* __restrict__ z) {
    int tid = threadIdx.x;
    int t = tid & 3;
    int e_ = blockIdx.x * 64 + (tid >> 2);
    if (e_ >= M_EDGES) return;
    int s = off[e_], e = off[e_ + 1];
    float4 a0 = {0,0,0,0}, a1 = {0,0,0,0}, a2 = {0,0,0,0}, a3 = {0,0,0,0};
    int j = s;
    for (; j + 4 <= e; j += 4) {
        float4 g0 = *(const float4*)(y + (long)idx[j] * 16 + t * 4);
        float4 g1 = *(const float4*)(y + (long)idx[j + 1] * 16 + t * 4);
        float4 g2 = *(const float4*)(y + (long)idx[j + 2] * 16 + t * 4);
        float4 g3 = *(const float4*)(y + (long)idx[j + 3] * 16 + t * 4);
        a0.x += g0.x; a0.y += g0.y; a0.z += g0.z; a0.w += g0.w;
        a1.x += g1.x; a1.y += g1.y; a1.z += g1.z; a1.w += g1.w;
        a2.x += g2.x; a2.y += g2.y; a2.z += g2.z; a2.w += g2.w;
        a3.x += g3.x; a3.y += g3.y; a3.z += g3.z; a3.w += g3.w;
    }
    for (; j < e; ++j) {
        float4 g0 = *(const float4*)(y + (long)idx[j] * 16 + t * 4);
        a0.x += g0.x; a0.y += g0.y; a0.z += g0.z; a0.w += g0.w;
    }
    float4 acc;
    acc.x = a0.x + a1.x + a2.x + a3.x;
    acc.y = a0.y + a1.y + a2.y + a3.y;
    acc.z = a0.z + a1.z + a2.z + a3.z;
    acc.w = a0.w + a1.w + a2.w + a3.w;
    *(float4*)(z + (long)e_ * 16 + t * 4) = acc;
}

// node readout over z rows (64B each): 4 threads per node, float4 per thread.
template<bool FIRST>
__global__ __launch_bounds__(256) void gather_z(const int* __restrict__ off,
        const int* __restrict__ idx, const float* __restrict__ z,
        const float* __restrict__ dinv, const float* __restrict__ hb,
        float* __restrict__ on) {
    int tid = threadIdx.x;
    int t = tid & 3;
    int n = blockIdx.x * 64 + (tid >> 2);
    int s = off[n], e = off[n + 1];
    float4 a0 = {0,0,0,0}, a1 = {0,0,0,0}, a2 = {0,0,0,0}, a3 = {0,0,0,0};
    int j = s;
    for (; j + 4 <= e; j += 4) {
        float4 g0 = *(const float4*)(z + (long)idx[j] * 16 + t * 4);
        float4 g1 = *(const float4*)(z + (long)idx[j + 1] * 16 + t * 4);
        float4 g2 = *(const float4*)(z + (long)idx[j + 2] * 16 + t * 4);
        float4 g3 = *(const float4*)(z + (long)idx[j + 3] * 16 + t * 4);
        a0.x += g0.x; a0.y += g0.y; a0.z += g0.z; a0.w += g0.w;
        a1.x += g1.x; a1.y += g1.y; a1.z += g1.z; a1.w += g1.w;
        a2.x += g2.x; a2.y += g2.y; a2.z += g2.z; a2.w += g2.w;
        a3.x += g3.x; a3.y += g3.y; a3.z += g3.z; a3.w += g3.w;
    }
    for (; j < e; ++j) {
        float4 g0 = *(const float4*)(z + (long)idx[j] * 16 + t * 4);
        a0.x += g0.x; a0.y += g0.y; a0.z += g0.z; a0.w += g0.w;
    }
    float di = dinv[n];
    float4 acc;
    acc.x = (a0.x + a1.x + a2.x + a3.x) * di;
    acc.y = (a0.y + a1.y + a2.y + a3.y) * di;
    acc.z = (a0.z + a1.z + a2.z + a3.z) * di;
    acc.w = (a0.w + a1.w + a2.w + a3.w) * di;
    float* op = on + (long)n * 16 + t * 4;
    if (FIRST) {
        float4 b;
#pragma unroll
        for (int k = 0; k < 4; ++k) {
            int c = t * 4 + k;
            ((float*)&b)[k] = (c < NCLS) ? hb[c] : 0.f;
        }
        *(float4*)op = (float4){acc.x + b.x, acc.y + b.y, acc.z + b.z, acc.w + b.w};
    } else {
        float4 old = *(float4*)op;
        *(float4*)op = (float4){old.x + acc.x, old.y + acc.y, old.z + acc.z, old.w + acc.w};
    }
}

// ---------------- single-A-plane MFMA GEMM, 128x128 tile, bf16 output ----------------
template<int K>
__global__ __launch_bounds__(256) void gemm128(const unsigned short* __restrict__ Ahg,
        const unsigned short* __restrict__ Bhg, const unsigned short* __restrict__ Blg,
        const float* __restrict__ bias, unsigned short* __restrict__ C,
        float* __restrict__ stats) {
    constexpr int KQ = K >> 3;
    __shared__ __align__(16) unsigned short Asl[16 * 512];   // 16 KB
    __shared__ __align__(16) unsigned short Bsl[32 * 512];   // 32 KB
    float* lsum = (float*)Asl;
    float* lsq  = lsum + 128;
    int tid = threadIdx.x;
    int lane = tid & 63, w = tid >> 6;
    int bx = blockIdx.x;
    int col0 = blockIdx.y * 128;
    int colblk0 = blockIdx.y * 2;
    int lm = lane & 15, lq = lane >> 4;
    int rbw = w >> 1;
    int rw = (w & 1) * 32;
    f4v acc[2][8];
#pragma unroll
    for (int i = 0; i < 2; ++i)
#pragma unroll
        for (int j = 0; j < 8; ++j) acc[i][j] = (f4v){0.f, 0.f, 0.f, 0.f};

    for (int ks = 0; ks < K / 64; ++ks) {
        int kq0 = ks * 8;
#pragma unroll
        for (int t = 0; t < 4; ++t) {
            int a = w * 4 + t;
            int rb = a >> 3, kqo = a & 7;
            const unsigned short* g = Ahg
                + ((long)((bx * 2 + rb) * KQ + kq0 + kqo) * 64 + lane) * 8;
            __builtin_amdgcn_global_load_lds(
                (const __attribute__((address_space(1))) void*)g,
                (__attribute__((address_space(3))) void*)(Asl + a * 512), 16, 0, 0);
        }
#pragma unroll
        for (int u = 0; u < 8; ++u) {
            int b = w * 8 + u;
            const unsigned short* g = ((b >> 4) ? Blg : Bhg)
                + ((long)((colblk0 + ((b >> 3) & 1)) * KQ + kq0 + (b & 7)) * 64 + lane) * 8;
            __builtin_amdgcn_global_load_lds(
                (const __attribute__((address_space(1))) void*)g,
                (__attribute__((address_space(3))) void*)(Bsl + b * 512), 16, 0, 0);
        }
        __syncthreads();
#pragma unroll
        for (int kk = 0; kk < 2; ++kk) {
            s8v ah[2];
#pragma unroll
            for (int i = 0; i < 2; ++i)
                ah[i] = *(const s8v*)&Asl[(rbw * 8 + kk * 4 + lq) * 512
                                          + (rw + i * 16 + lm) * 8];
#pragma unroll
            for (int j = 0; j < 8; ++j) {
                int cb = j >> 2;
                int c64 = (j & 3) * 16 + lm;
                s8v bh = *(const s8v*)&Bsl[(cb * 8 + kk * 4 + lq) * 512 + c64 * 8];
                s8v bl = *(const s8v*)&Bsl[(16 + cb * 8 + kk * 4 + lq) * 512 + c64 * 8];
#pragma unroll
                for (int i = 0; i < 2; ++i) {
                    acc[i][j] = __builtin_amdgcn_mfma_f32_16x16x32_bf16(ah[i], bl, acc[i][j], 0, 0, 0);
                    acc[i][j] = __builtin_amdgcn_mfma_f32_16x16x32_bf16(ah[i], bh, acc[i][j], 0, 0, 0);
                }
            }
        }
        __syncthreads();
    }
    if (tid < 128) { lsum[tid] = 0.f; lsq[tid] = 0.f; }
    __syncthreads();
#pragma unroll
    for (int j = 0; j < 8; ++j) {
        int lc = j * 16 + lm;
        int col = col0 + lc;
        float bsv = bias[col];
        float s = 0.f, sq = 0.f;
#pragma unroll
        for (int i = 0; i < 2; ++i) {
#pragma unroll
            for (int reg = 0; reg < 4; ++reg) {
                long row = (long)bx * 128 + rbw * 64 + rw + i * 16 + lq * 4 + reg;
                if (row < N_NODES) {
                    unsigned short hv = f2bf(acc[i][j][reg] + bsv);
                    float vr = bf2f(hv);
                    C[row * HID + col] = hv;
                    s += vr;
                    sq += vr * vr;
                }
            }
        }
        atomicAdd(&lsum[lc], s);
        atomicAdd(&lsq[lc], sq);
    }
    __syncthreads();
    if (tid < 128) {
        atomicAdd(&stats[col0 + tid], lsum[tid]);
        atomicAdd(&stats[HID + col0 + tid], lsq[tid]);
    }
}

// ---------------- readout (onodes stride 16) ----------------
__global__ __launch_bounds__(256) void readout_accum(const float* __restrict__ on,
                                                     const int* __restrict__ ab,
                                                     float* __restrict__ racc,
                                                     float* __restrict__ rcnt) {
    __shared__ float lacc[NG * NCLS];
    __shared__ float lcnt[NG];
    int tid = threadIdx.x;
    for (int i = tid; i < NG * NCLS; i += 256) lacc[i] = 0.f;
    if (tid < NG) lcnt[tid] = 0.f;
    __syncthreads();
    int n = blockIdx.x * 256 + tid;
    if (n < N_NODES) {
        int b = ab[n];
        atomicAdd(&lcnt[b], 1.0f);
        for (int c = 0; c < NCLS; ++c) atomicAdd(&lacc[b * NCLS + c], on[(long)n * 16 + c]);
    }
    __syncthreads();
    if (tid < NG && lcnt[tid] > 0.f) {
        atomicAdd(&rcnt[tid], lcnt[tid]);
        for (int c = 0; c < NCLS; ++c) atomicAdd(&racc[tid * NCLS + c], lacc[tid * NCLS + c]);
    }
}

__global__ void readout_final(const float* __restrict__ racc, const float* __restrict__ rcnt,
                              float* __restrict__ out) {
    int i = blockIdx.x * 256 + threadIdx.x;
    if (i < NG * NCLS) out[i] = racc[i] / fmaxf(rcnt[i / NCLS], 1.0f);
}

// ---------------- launch ----------------
extern "C" void kernel_launch(void* const* d_in, const int* in_sizes, int n_in,
                              void* d_out, int out_size, void* d_ws, size_t ws_size,
                              hipStream_t stream) {
    const float* X         = (const float*)d_in[0];
    const int*   node_idx  = (const int*)d_in[1];
    const int*   edge_idx  = (const int*)d_in[2];
    const int*   all_batch = (const int*)d_in[3];
    const float* W1[2]  = {(const float*)d_in[4],  (const float*)d_in[12]};
    const float* b1[2]  = {(const float*)d_in[5],  (const float*)d_in[13]};
    const float* g1[2]  = {(const float*)d_in[6],  (const float*)d_in[14]};
    const float* be1[2] = {(const float*)d_in[7],  (const float*)d_in[15]};
    const float* W2[2]  = {(const float*)d_in[8],  (const float*)d_in[16]};
    const float* b2[2]  = {(const float*)d_in[9],  (const float*)d_in[17]};
    const float* bng[2] = {(const float*)d_in[10], (const float*)d_in[18]};
    const float* bnb[2] = {(const float*)d_in[11], (const float*)d_in[19]};
    const float* headW  = (const float*)d_in[20];
    const float* headb  = (const float*)d_in[21];
    float* out = (float*)d_out;

    char* base = (char*)d_ws;
    size_t off = 0;
    auto alloc = [&](size_t bytes) -> void* {
        size_t o = (off + 255) & ~(size_t)255;
        off = o + bytes;
        return (void*)(base + o);
    };

    const int ZINTS = M_EDGES + N_NODES;
    const int ZTOT  = ZINTS + 4 * 2 * HID + NG * NCLS + NG;
    int* ibase  = (int*)alloc((size_t)ZTOT * 4);
    int* cnt_e  = ibase;
    int* cnt_n  = cnt_e + M_EDGES;
    float* statsall = (float*)(ibase + ZINTS);
    float* racc     = statsall + 4 * 2 * HID;
    float* rcnt     = racc + NG * NCLS;

    int* off_e  = (int*)alloc((M_EDGES + 1) * 4);
    int* off_n  = (int*)alloc((N_NODES + 1) * 4);
    int* gcur_e = (int*)alloc(NBE * 4);
    int* gcur_n = (int*)alloc(NBN * 4);
    int* idx_e  = (int*)alloc((size_t)NNZ_CNT * 4);
    int* idx_n  = (int*)alloc((size_t)NNZ_CNT * 4);
    unsigned* stg_e = (unsigned*)alloc((size_t)NNZ_CNT * 4);
    unsigned* stg_n = (unsigned*)alloc((size_t)NNZ_CNT * 4);
    float* dinv = (float*)alloc((size_t)N_NODES * 4);

    unsigned short* Xb = (unsigned short*)alloc((size_t)N_NODES * FT_DIM * 2);
    unsigned short* Eb = (unsigned short*)alloc((size_t)M_EDGES * HID * 2);
    unsigned short* Ph = (unsigned short*)alloc((size_t)M_PAD * HID * 2);
    unsigned short* Ahp = (unsigned short*)alloc((size_t)M_PAD * HID * 2);
    unsigned short* Hb  = (unsigned short*)alloc((size_t)N_NODES * HID * 2);
    unsigned short* Tb  = (unsigned short*)alloc((size_t)N_NODES * HID * 2);
    float* onodes = (float*)alloc((size_t)N_NODES * 16 * 4);
    float* ybuf   = (float*)alloc((size_t)N_NODES * 16 * 4);
    float* zbuf   = (float*)alloc((size_t)M_EDGES * 16 * 4);
    unsigned short* Wp[4][2];
    int WK[4] = {FT_DIM, HID, HID, HID};
    for (int m = 0; m < 4; ++m) {
        Wp[m][0] = (unsigned short*)alloc((size_t)WK[m] * HID * 2);
        Wp[m][1] = (unsigned short*)alloc((size_t)WK[m] * HID * 2);
    }

    const int nnz_blocks = (NNZ_CNT + 255) / 256;
    const int n8 = N_NODES * HID / 8;
    const dim3 ggrid(M_PAD / 128, 2);

    // --- CSR build (bucketed counting sort) + degree norm + weight prep ---
    fzero<<<(ZTOT + 255) / 256, 256, 0, stream>>>((float*)ibase, ZTOT);
    count_kernel<<<nnz_blocks, 256, 0, stream>>>(node_idx, edge_idx, cnt_e, cnt_n);
    exscan2<<<2, 1024, 0, stream>>>(cnt_e, off_e, cnt_n, off_n, gcur_e, gcur_n);
    partition_kernel<<<(NNZ_CNT + 8191) / 8192, 256, 0, stream>>>(node_idx, edge_idx,
                                                                  gcur_e, gcur_n, stg_e, stg_n);
    bucket_fill<<<NBE + NBN, 256, 0, stream>>>(off_e, off_n, stg_e, stg_n, idx_e, idx_n);
    dinv_kernel<<<(N_NODES + 255) / 256, 256, 0, stream>>>(off_n, idx_n, cnt_e, dinv);
    WPA wpa;
    wpa.W[0] = W1[0]; wpa.W[1] = W2[0]; wpa.W[2] = W1[1]; wpa.W[3] = W2[1];
    for (int m = 0; m < 4; ++m) { wpa.h[m] = Wp[m][0]; wpa.l[m] = Wp[m][1]; }
    wprep_all<<<dim3(256, 4), 256, 0, stream>>>(wpa);
    fsplit<<<(N_NODES * FT_DIM / 4 + 255) / 256, 256, 0, stream>>>((const float4*)X,
                                                                   (u4v*)Xb, N_NODES * FT_DIM / 4);

    // ---------------- layer 0 ----------------
    gather_e128<<<M_EDGES / 4, 256, 0, stream>>>(off_e, idx_e, Xb, Eb);
    gather_n128_planes<<<N_NODES / 4, 256, 0, stream>>>(off_n, idx_n, Eb, Ph);
    gemm128<FT_DIM><<<ggrid, 256, 0, stream>>>(Ph, Wp[0][0], Wp[0][1], b1[0], Tb,
                                               statsall + 0 * 512);
    bn_split_blk<<<N_NODES / 64, 256, 0, stream>>>(Tb, statsall + 0 * 512, g1[0], be1[0], Ahp);
    gemm128<HID><<<ggrid, 256, 0, stream>>>(Ahp, Wp[1][0], Wp[1][1], b2[0], Tb,
                                            statsall + 1 * 512);
    bn_rowmajor<<<(n8 + 255) / 256, 256, 0, stream>>>((const u8v*)Tb, statsall + 1 * 512,
                                                      bng[0], bnb[0], (u8v*)Hb, n8);
    // single full-width pooling gather + y-path readout
    gather_e256<<<M_EDGES / 4, 256, 0, stream>>>(off_e, idx_e, Hb, Eb);
    head_y<<<(N_NODES + 255) / 256, 256, 0, stream>>>(Hb, headW, ybuf);
    gather_e_y<<<(M_EDGES + 63) / 64, 256, 0, stream>>>(off_e, idx_e, ybuf, zbuf);
    gather_z<true><<<N_NODES / 64, 256, 0, stream>>>(off_n, idx_n, zbuf, dinv, headb, onodes);
    gather_n256_planes<<<N_NODES / 4, 256, 0, stream>>>(off_n, idx_n, Eb, Ph);

    // ---------------- layer 1 ----------------
    gemm128<HID><<<ggrid, 256, 0, stream>>>(Ph, Wp[2][0], Wp[2][1], b1[1], Tb,
                                            statsall + 2 * 512);
    bn_split_blk<<<N_NODES / 64, 256, 0, stream>>>(Tb, statsall + 2 * 512, g1[1], be1[1], Ahp);
    gemm128<HID><<<ggrid, 256, 0, stream>>>(Ahp, Wp[3][0], Wp[3][1], b2[1], Tb,
                                            statsall + 3 * 512);
    bn_rowmajor<<<(n8 + 255) / 256, 256, 0, stream>>>((const u8v*)Tb, statsall + 3 * 512,
                                                      bng[1], bnb[1], (u8v*)Hb, n8);
    // layer-1 readout: entirely via y-path (no full-width edge gather needed)
    head_y<<<(N_NODES + 255) / 256, 256, 0, stream>>>(Hb, headW + (size_t)HID * NCLS, ybuf);
    gather_e_y<<<(M_EDGES + 63) / 64, 256, 0, stream>>>(off_e, idx_e, ybuf, zbuf);
    gather_z<false><<<N_NODES / 64, 256, 0, stream>>>(off_n, idx_n, zbuf, dinv, nullptr, onodes);

    // ---------------- readout ----------------
    readout_accum<<<(N_NODES + 255) / 256, 256, 0, stream>>>(onodes, all_batch, racc, rcnt);
    readout_final<<<(NG * NCLS + 255) / 256, 256, 0, stream>>>(racc, rcnt, out);
}